// Round 4
// baseline (634.608 us; speedup 1.0000x reference)
//
#include <hip/hip_runtime.h>
#include <hip/hip_bf16.h>

#define B_ 8
#define C_ 256
#define H_ 64
#define W_ 64
#define HW_ 4096
#define E_ 32
#define K_ 8192
#define N_ 32768          // B*H*W
#define NCHUNK 4
#define KC_ (K_ / NCHUNK) // 2048

#define DECAY_ 0.99f
#define OMD_   0.01f
#define EPS_   1e-5f
#define BETA_  0.25f

// ---- output layout (fp32 elements, concatenated in reference return order) ----
#define O_ZQ   0          // [B,E,H,W] 1048576
#define O_IDX  1048576    // [B,H,W]   32768
#define O_QL   1081344    // scalar    1
#define O_NEMB 1081345    // [K,E]     262144
#define O_NCS  1343489    // [K]       8192
#define O_NW   1351681    // [K,E]     262144
                          // total     1613825 floats

// ---- workspace layout (float offsets into d_ws); total ~3.3 MB ----
#define WS_EN   0u        // K*E fp32 normalized embedding      [0,      262144)
#define WS_BSC  262144u   // NCHUNK*N best scores               [262144, 393216)
#define WS_BIX  393216u   // NCHUNK*N best indices (int)        [393216, 524288)
#define WS_IDX  524288u   // N final indices (int)              [524288, 557056)
#define WS_CNT  557056u   // K counts (zeroed)                  [557056, 565248)
#define WS_DW   565248u   // K*E dw (zeroed)                    [565248, 827392)
#define WS_SCAL 827392u   // [0]=n sum, [1]=qloss sq sum (zeroed)

// ---------------- K0: normalize embedding rows (fp32) ----------------
__global__ __launch_bounds__(256) void k_norm_emb(const float* __restrict__ emb,
                                                  float* __restrict__ en) {
    int k = blockIdx.x * 256 + threadIdx.x;
    if (k >= K_) return;
    const float4* r = (const float4*)(emb + (size_t)k * E_);
    float4 v[8];
    float ss = 0.f;
#pragma unroll
    for (int i = 0; i < 8; i++) {
        v[i] = r[i];
        ss += v[i].x * v[i].x + v[i].y * v[i].y + v[i].z * v[i].z + v[i].w * v[i].w;
    }
    float inv = 1.0f / fmaxf(sqrtf(ss), 1e-12f);
    float4* o = (float4*)(en + (size_t)k * E_);
#pragma unroll
    for (int i = 0; i < 8; i++) {
        o[i] = make_float4(v[i].x * inv, v[i].y * inv, v[i].z * inv, v[i].w * inv);
    }
}

// Shared z-compute: stage WqT into lds (8192 floats), compute z[32] for pixel n.
// Identical instruction sequence in score & scatter kernels -> identical fp32 bits.
__device__ __forceinline__ void compute_z(const float* __restrict__ x,
                                          const float* __restrict__ Wq,
                                          const float* __restrict__ bq,
                                          float* lds, int tid, int n,
                                          float4 zr[8]) {
#pragma unroll
    for (int i = 0; i < (C_ * E_) / 256; i++) {
        int g = i * 256 + tid;       // g = e*C_ + c  (Wq is [E,C])
        int e = g >> 8;
        int c = g & (C_ - 1);
        lds[c * E_ + e] = Wq[g];
    }
    __syncthreads();

    int b  = n >> 12;
    int hw = n & (HW_ - 1);
    const float* xp = x + (size_t)b * C_ * HW_ + hw;

    float4 acc[8];
#pragma unroll
    for (int i = 0; i < 8; i++) acc[i] = make_float4(0.f, 0.f, 0.f, 0.f);

    const float4* w4 = (const float4*)lds;
#pragma unroll 4
    for (int c = 0; c < C_; c++) {
        float xv = xp[(size_t)c * HW_];
#pragma unroll
        for (int i = 0; i < 8; i++) {
            float4 w = w4[c * 8 + i];
            acc[i].x += xv * w.x; acc[i].y += xv * w.y;
            acc[i].z += xv * w.z; acc[i].w += xv * w.w;
        }
    }
#pragma unroll
    for (int i = 0; i < 8; i++) {
        acc[i].x += bq[i * 4 + 0];
        acc[i].y += bq[i * 4 + 1];
        acc[i].z += bq[i * 4 + 2];
        acc[i].w += bq[i * 4 + 3];
        zr[i] = acc[i];
    }
    __syncthreads();   // done reading WqT from lds; safe to reuse
}

// ---------------- K1: fused z-GEMM + scores + argmax over one K-chunk ----------------
__global__ __launch_bounds__(256) void k_score_fused(const float* __restrict__ x,
                                                     const float* __restrict__ Wq,
                                                     const float* __restrict__ bq,
                                                     const float* __restrict__ en,
                                                     float* __restrict__ bsc,
                                                     int* __restrict__ bix) {
    __shared__ float lds[C_ * E_];   // 32 KB: WqT first, then en tiles
    int tid = threadIdx.x;
    int n   = blockIdx.x * 256 + tid;

    float4 zr[8];
    compute_z(x, Wq, bq, lds, tid, n, zr);

    int chunk = blockIdx.y;
    int kbase = chunk * KC_;

    float best = -3.0e38f;
    int   bidx = 0;

    for (int t = 0; t < KC_ / 256; t++) {
        const float4* src = (const float4*)en + (size_t)(kbase + t * 256) * (E_ / 4);
        float4* dst = (float4*)lds;
#pragma unroll
        for (int i = 0; i < 8; i++) dst[i * 256 + tid] = src[i * 256 + tid];
        __syncthreads();

#pragma unroll 2
        for (int r = 0; r < 256; r++) {
            const float4* er = (const float4*)(lds + r * E_);
            float sx = 0.f, sy = 0.f, sz = 0.f, sw = 0.f;
#pragma unroll
            for (int i = 0; i < 8; i++) {
                float4 e4 = er[i];
                sx += zr[i].x * e4.x; sy += zr[i].y * e4.y;
                sz += zr[i].z * e4.z; sw += zr[i].w * e4.w;
            }
            float s = (sx + sy) + (sz + sw);
            int k = kbase + t * 256 + r;
            if (s > best) { best = s; bidx = k; }  // strict > : first max wins
        }
        __syncthreads();
    }
    bsc[(size_t)chunk * N_ + n] = best;
    bix[(size_t)chunk * N_ + n] = bidx;
}

// ---------------- K2: combine chunk argmaxes ----------------
__global__ __launch_bounds__(256) void k_combine(const float* __restrict__ bsc,
                                                 const int* __restrict__ bix,
                                                 int* __restrict__ idxs,
                                                 float* __restrict__ out_idx) {
    int n = blockIdx.x * 256 + threadIdx.x;
    if (n >= N_) return;
    float best = bsc[n];
    int   bi   = bix[n];
#pragma unroll
    for (int c = 1; c < NCHUNK; c++) {
        float s = bsc[(size_t)c * N_ + n];
        int  k2 = bix[(size_t)c * N_ + n];
        if (s > best) { best = s; bi = k2; }  // ascending chunk order: lowest k on ties
    }
    idxs[n] = bi;
    out_idx[n] = (float)bi;
}

// ---------------- K3: recompute z, gather z_q, qloss, scatter counts/dw ----------------
__global__ __launch_bounds__(256) void k_scatter(const float* __restrict__ x,
                                                 const float* __restrict__ Wq,
                                                 const float* __restrict__ bq,
                                                 const int* __restrict__ idxs,
                                                 const float* __restrict__ emb,
                                                 float* __restrict__ out_zq,
                                                 float* __restrict__ dw,
                                                 float* __restrict__ cnt,
                                                 float* __restrict__ scal) {
    __shared__ float lds[C_ * E_];
    int tid = threadIdx.x;
    int n   = blockIdx.x * 256 + tid;

    float4 zr[8];
    compute_z(x, Wq, bq, lds, tid, n, zr);
    const float* zf = (const float*)zr;

    int b   = n >> 12;
    int hw  = n & (HW_ - 1);
    int idx = idxs[n];
    idx = idx < 0 ? 0 : (idx > K_ - 1 ? K_ - 1 : idx);   // defensive clamp
    const float* er = emb + (size_t)idx * E_;
    float* o = out_zq + (size_t)b * E_ * HW_ + hw;

    float sq = 0.f;
#pragma unroll
    for (int e = 0; e < E_; e++) {
        float qf = er[e];
        float zv = zf[e];
        float d = qf - zv;
        sq += d * d;
        o[(size_t)e * HW_] = qf;
        atomicAdd(dw + (size_t)idx * E_ + e, zv);
    }
    atomicAdd(cnt + idx, 1.0f);

    // block reduction of sq
#pragma unroll
    for (int off = 32; off > 0; off >>= 1) sq += __shfl_down(sq, off);
    __shared__ float red[4];
    int lane = tid & 63, wid = tid >> 6;
    if (lane == 0) red[wid] = sq;
    __syncthreads();
    if (tid == 0) atomicAdd(scal + 1, red[0] + red[1] + red[2] + red[3]);
}

// ---------------- K4: EMA cluster size + n reduction ----------------
__global__ __launch_bounds__(256) void k_ema_cs(const float* __restrict__ cs,
                                                const float* __restrict__ cnt,
                                                float* __restrict__ out_ncs,
                                                float* __restrict__ scal) {
    int tid = threadIdx.x;
    int k = blockIdx.x * 256 + tid;
    float v = DECAY_ * cs[k] + OMD_ * cnt[k];
    out_ncs[k] = v;

    float s = v;
#pragma unroll
    for (int off = 32; off > 0; off >>= 1) s += __shfl_down(s, off);
    __shared__ float red[4];
    int lane = tid & 63, wid = tid >> 6;
    if (lane == 0) red[wid] = s;
    __syncthreads();
    if (tid == 0) atomicAdd(scal + 0, red[0] + red[1] + red[2] + red[3]);
}

// ---------------- K5: new_w + smoothed division + qloss write ----------------
__global__ __launch_bounds__(256) void k_final(const float* __restrict__ ew,
                                               const float* __restrict__ dw,
                                               const float* __restrict__ cs,
                                               const float* __restrict__ cnt,
                                               const float* __restrict__ scal,
                                               float* __restrict__ out_nw,
                                               float* __restrict__ out_nemb,
                                               float* __restrict__ out_ql) {
    int j = blockIdx.x * 256 + threadIdx.x;  // < K_*E_
    float v = DECAY_ * ew[j] + OMD_ * dw[j];     // new_w
    out_nw[j] = v;
    float nsum = scal[0];
    int k = j >> 5;
    float csk = DECAY_ * cs[k] + OMD_ * cnt[k];  // new_cs (recomputed)
    float denom = (csk + EPS_) / (nsum + (float)K_ * EPS_) * nsum;
    out_nemb[j] = v / denom;
    if (j == 0) {
        out_ql[0] = BETA_ * scal[1] / (float)(B_ * E_ * HW_);
    }
}

extern "C" void kernel_launch(void* const* d_in, const int* in_sizes, int n_in,
                              void* d_out, int out_size, void* d_ws, size_t ws_size,
                              hipStream_t stream) {
    const float* x   = (const float*)d_in[0];
    const float* Wq  = (const float*)d_in[1];
    const float* bq  = (const float*)d_in[2];
    const float* emb = (const float*)d_in[3];
    const float* cs  = (const float*)d_in[4];
    const float* ew  = (const float*)d_in[5];
    float* out = (float*)d_out;
    float* ws = (float*)d_ws;

    // zero accumulators (harness poisons ws with 0xAA before every launch)
    hipMemsetAsync(ws + WS_CNT, 0, (size_t)(K_ + K_ * E_) * sizeof(float), stream);
    hipMemsetAsync(ws + WS_SCAL, 0, 2 * sizeof(float), stream);

    k_norm_emb<<<K_ / 256, 256, 0, stream>>>(emb, ws + WS_EN);
    k_score_fused<<<dim3(N_ / 256, NCHUNK), 256, 0, stream>>>(
        x, Wq, bq, ws + WS_EN, ws + WS_BSC, (int*)(ws + WS_BIX));
    k_combine<<<N_ / 256, 256, 0, stream>>>(ws + WS_BSC, (int*)(ws + WS_BIX),
                                            (int*)(ws + WS_IDX), out + O_IDX);
    k_scatter<<<N_ / 256, 256, 0, stream>>>(x, Wq, bq, (const int*)(ws + WS_IDX), emb,
                                            out + O_ZQ, ws + WS_DW, ws + WS_CNT,
                                            ws + WS_SCAL);
    k_ema_cs<<<K_ / 256, 256, 0, stream>>>(cs, ws + WS_CNT, out + O_NCS, ws + WS_SCAL);
    k_final<<<(K_ * E_) / 256, 256, 0, stream>>>(ew, ws + WS_DW, cs, ws + WS_CNT,
                                                 ws + WS_SCAL, out + O_NW,
                                                 out + O_NEMB, out + O_QL);
}